// Round 12
// baseline (272.534 us; speedup 1.0000x reference)
//
#include <hip/hip_runtime.h>
#include <hip/hip_bf16.h>
#include <stdint.h>

#define SEGN 8
#define LSEG 1024
#define SS   8192
#define EE   1152
#define HH   16
#define DD   72
#define DP   96
#define E3   3456

typedef __attribute__((ext_vector_type(8)))  __bf16 bf16x8;
typedef __attribute__((ext_vector_type(4)))  float  f32x4;
typedef __attribute__((ext_vector_type(16))) float  f32x16;
typedef __attribute__((ext_vector_type(4)))  unsigned int u32x4;

__device__ __forceinline__ short f2b(float x) {
  __hip_bfloat16 h = __float2bfloat16(x);
  return __builtin_bit_cast(short, h);
}
__device__ __forceinline__ float b2f(short x) {
  return __bfloat162float(__builtin_bit_cast(__hip_bfloat16, x));
}
__device__ __forceinline__ unsigned int pk2(float x, float y) {
  return (unsigned int)(unsigned short)f2b(x) |
         ((unsigned int)(unsigned short)f2b(y) << 16);
}
__device__ __forceinline__ void gload16(const void* g, void* l) {
  __builtin_amdgcn_global_load_lds(
      (const __attribute__((address_space(1))) unsigned int*)g,
      (__attribute__((address_space(3))) unsigned int*)l, 16, 0, 0);
}

#define BAR() __builtin_amdgcn_s_barrier()

// ---------------- fp32 -> bf16 convert ----------------
__global__ void k_cvt(const float* __restrict__ in, short* __restrict__ out, int n4) {
  int i = blockIdx.x * blockDim.x + threadIdx.x;
  int stride = gridDim.x * blockDim.x;
  for (; i < n4; i += stride) {
    float4 v = reinterpret_cast<const float4*>(in)[i];
    short4 o;
    o.x = f2b(v.x); o.y = f2b(v.y); o.z = f2b(v.z); o.w = f2b(v.w);
    reinterpret_cast<short4*>(out)[i] = o;
  }
}

// ---------------- 128x128 ring-4 GEMM, 2 K-tiles per barrier interval -----------
// 256 thr = 4 waves (2m x 2n), wave tile 64x64, acc[4][4], BK=32, NT=K/32 (even).
// LDS [4 bufs][128 rows][32 shorts] per side = 64KB total -> 2 blocks/CU.
// Staging (R11-proven): chunk c -> row c>>2, slot c&3; logical slot ^= (row>>1)&3
//   on the GLOBAL source (LDS dest linear); 4 consecutive lanes = one 64B line.
// Read (R11-proven): byte = row*64 + ((kg ^ ((r16>>1)&3))<<4) -> conflict-free b128.
// Interval j (tiles 2j,2j+1): vmcnt(0) [the 8 outstanding loads ARE tiles 2j,2j+1,
//   issued one full interval ago] -> s_barrier -> STAGE(2j+2),STAGE(2j+3) ->
//   ds_read st0 + 16 MFMA -> ds_read st1 + 16 MFMA.
// Race-free: STAGE targets bufs whose readers (tiles 2j-2,2j-1) completed before
//   this interval's top barrier; intra-interval reads are disjoint bufs.
// 18 barriers per K-pass (was 36); 32 MFMA/wave per barrier (was 16).
template <int OUT_BF16>
__global__ __launch_bounds__(256, 4) void k_gemm128(
    const short* __restrict__ A, const short* __restrict__ B,
    const float* __restrict__ bias, void* __restrict__ Cout,
    int K, int N)
{
  __shared__ __align__(16) short Als[4][128 * 32];
  __shared__ __align__(16) short Bls[4][128 * 32];
  const int t = threadIdx.x;
  const int lane = t & 63, w = t >> 6;
  const int r16 = lane & 15, kg = lane >> 4;
  const int wm = w >> 1, wn = w & 1;
  const int m0 = blockIdx.x * 128, n0 = blockIdx.y * 128;
  const int NT = K >> 5;          // even (K=1152 -> 36)

  // staging sources (consecutive-lane coalesced, inverse-swizzled slot)
  const short* pa[2];
  const short* pb[2];
#pragma unroll
  for (int g = 0; g < 2; ++g) {
    int c = t + g * 256;
    int row = c >> 2;
    int sl = (c & 3) ^ ((row >> 1) & 3);
    pa[g] = A + (size_t)(m0 + row) * K + sl * 8;
    pb[g] = B + (size_t)(n0 + row) * K + sl * 8;
  }

#define STAGE(buf, kt_) do { \
    _Pragma("unroll") \
    for (int g = 0; g < 2; ++g) { \
      gload16(pa[g] + (kt_) * 32, (char*)Als[buf] + (t + g * 256) * 16); \
      gload16(pb[g] + (kt_) * 32, (char*)Bls[buf] + (t + g * 256) * 16); \
    } } while (0)

  // swizzled read bases: frag row = w?*64 + mi*16 + r16; (row>>1)&3 == (r16>>1)&3
  const int xorv = (kg ^ ((r16 >> 1) & 3)) << 4;
  const int aoff = (wm * 64 + r16) * 64 + xorv;
  const int boff = (wn * 64 + r16) * 64 + xorv;

  f32x4 acc[4][4] = {};

  // prologue: tiles 0,1 in flight (8 loads/thread)
  STAGE(0, 0);
  STAGE(1, 1);

  const int NI = NT >> 1;
  for (int j = 0; j < NI; ++j) {
    const int kt0 = 2 * j;
    const int b0 = kt0 & 3, b1 = (kt0 + 1) & 3;

    asm volatile("s_waitcnt vmcnt(0)" ::: "memory");  // tiles kt0,kt0+1 landed
    BAR();
    __builtin_amdgcn_sched_barrier(0);

    // prefetch next interval's tiles (bufs' readers finished before the barrier)
    if (kt0 + 2 < NT) STAGE((kt0 + 2) & 3, kt0 + 2);
    if (kt0 + 3 < NT) STAGE((kt0 + 3) & 3, kt0 + 3);

    // sub-tile 0
    {
      const char* Ab = (const char*)Als[b0] + aoff;
      const char* Bb = (const char*)Bls[b0] + boff;
      bf16x8 a_[4], b_[4];
#pragma unroll
      for (int i = 0; i < 4; ++i) {
        a_[i] = *(const bf16x8*)(Ab + i * 1024);
        b_[i] = *(const bf16x8*)(Bb + i * 1024);
      }
      __builtin_amdgcn_s_setprio(1);
#pragma unroll
      for (int mi = 0; mi < 4; ++mi)
#pragma unroll
        for (int ni = 0; ni < 4; ++ni)
          acc[mi][ni] = __builtin_amdgcn_mfma_f32_16x16x32_bf16(a_[mi], b_[ni], acc[mi][ni], 0, 0, 0);
      __builtin_amdgcn_s_setprio(0);
    }
    // sub-tile 1
    {
      const char* Ab = (const char*)Als[b1] + aoff;
      const char* Bb = (const char*)Bls[b1] + boff;
      bf16x8 a_[4], b_[4];
#pragma unroll
      for (int i = 0; i < 4; ++i) {
        a_[i] = *(const bf16x8*)(Ab + i * 1024);
        b_[i] = *(const bf16x8*)(Bb + i * 1024);
      }
      __builtin_amdgcn_s_setprio(1);
#pragma unroll
      for (int mi = 0; mi < 4; ++mi)
#pragma unroll
        for (int ni = 0; ni < 4; ++ni)
          acc[mi][ni] = __builtin_amdgcn_mfma_f32_16x16x32_bf16(a_[mi], b_[ni], acc[mi][ni], 0, 0, 0);
      __builtin_amdgcn_s_setprio(0);
    }
  }
#undef STAGE

  // epilogue
#pragma unroll
  for (int ni = 0; ni < 4; ++ni) {
    int col = n0 + wn * 64 + ni * 16 + r16;
    float bv = bias[col];
#pragma unroll
    for (int mi = 0; mi < 4; ++mi)
#pragma unroll
      for (int r = 0; r < 4; ++r) {
        int row = m0 + wm * 64 + mi * 16 + kg * 4 + r;
        float v = acc[mi][ni][r] + bv;
        if (OUT_BF16) ((short*)Cout)[(size_t)row * N + col] = f2b(v);
        else          ((float*)Cout)[(size_t)row * N + col] = v;
      }
  }
}

// ---------------- RoPE + Q/K/V repack ----------------
__global__ __launch_bounds__(256) void k_rope(
    const short* __restrict__ qkv, const float* __restrict__ cosb, const float* __restrict__ sinb,
    short* __restrict__ Qg, short* __restrict__ Kg, short* __restrict__ Vg)
{
  __shared__ short vt[72][64];
  const int b = blockIdx.x;
  const int seg = b >> 8, head = (b >> 4) & 15, pb = b & 15;
  const int pos0 = pb * 64;
  const int t = threadIdx.x;
  const int sh = seg * 16 + head;
  const float qscale = 0.17002540410995343f; // log2(e)/sqrt(72)

#pragma unroll
  for (int i = 0; i < 24; ++i) {
    int e = t + i * 256;
    int p = e / 96, d = e % 96;
    int s = seg * 1024 + pos0 + p;
    int ob = (sh * 1024 + pos0 + p) * 96 + d;
    short qo = 0, ko = 0;
    if (d < 72) {
      int base = s * E3 + head * 72;
      float c = cosb[s * 72 + d], sn = sinb[s * 72 + d];
      int d2 = d < 36 ? d + 36 : d - 36;
      float sgn = d < 36 ? -1.f : 1.f;
      float q1 = b2f(qkv[base + d]),        q2 = b2f(qkv[base + d2]);
      float k1 = b2f(qkv[base + 1152 + d]), k2 = b2f(qkv[base + 1152 + d2]);
      qo = f2b((q1 * c + sgn * q2 * sn) * qscale);
      ko = f2b(k1 * c + sgn * k2 * sn);
    }
    Qg[ob] = qo;
    Kg[ob] = ko;
  }
  for (int i = 0; i < 18; ++i) {
    int e = t + i * 256;
    int p = e / 72, d = e % 72;
    int s = seg * 1024 + pos0 + p;
    vt[d][p] = qkv[s * E3 + 2304 + head * 72 + d];
  }
  __syncthreads();
#pragma unroll
  for (int i = 0; i < 24; ++i) {
    int e = t + i * 256;
    int d = e >> 6, p = e & 63;
    short v;
    if (d < 72)       v = vt[d][p];
    else if (d == 72) v = (short)0x3F80;  // bf16 1.0 -> denominator column
    else              v = 0;
    Vg[(sh * 96 + d) * 1024 + pos0 + p] = v;
  }
}

// ---------------- Flash attention: swapped-QK 32x32, double-buffered async staging ----
#define KSS 104
#define VTS 72
__global__ __launch_bounds__(256, 2) void k_attn(
    const short* __restrict__ Qg, const short* __restrict__ Kg, const short* __restrict__ Vg,
    short* __restrict__ Og)
{
  __shared__ __align__(16) short Ks[2][64 * KSS];
  __shared__ __align__(16) short VT[2][96 * VTS];
  const int p_ = blockIdx.x;
  const int xcd = p_ & 7, rest = p_ >> 3;
  const int qb = rest & 7, shi = rest >> 3;
  const int sh = xcd * 16 + shi;
  const int seg = sh >> 4, head = sh & 15;
  const int t = threadIdx.x, lane = t & 63, wave = t >> 6;
  const int l31 = lane & 31, hi = lane >> 5;
  const int q0 = qb * 128 + wave * 32;

  bf16x8 qf[5];
  {
    const short* qp = Qg + ((size_t)(sh * 1024 + q0 + l31)) * 96 + hi * 8;
#pragma unroll
    for (int dm = 0; dm < 5; ++dm) qf[dm] = *(const bf16x8*)(qp + dm * 16);
  }

  const short* kbase = Kg + (size_t)sh * 1024 * 96;
  const short* vbase = Vg + (size_t)sh * 96 * 1024;
  int koff[4], voff[4];
#pragma unroll
  for (int i = 0; i < 4; ++i) {
    int c = t + i * 256;
    int kr = c / 13, kc8 = c - kr * 13;
    koff[i] = kr * 96 + ((kc8 == 12) ? 0 : kc8 * 8);
    int vr = c / 9, vc8 = c - vr * 9;
    voff[i] = vr * 1024 + ((vc8 == 8) ? 0 : vc8 * 8);
  }

  f32x16 acc0 = {}, acc1 = {}, acc2 = {};
  float Mrun = -1e30f;

  {
    const short* kp = kbase;
    const short* vp = vbase;
#pragma unroll
    for (int i = 0; i < 3; ++i) {
      gload16(kp + koff[i], (char*)Ks[0] + (t + i * 256) * 16);
      gload16(vp + voff[i], (char*)VT[0] + (t + i * 256) * 16);
    }
    if (t < 64) gload16(kp + koff[3], (char*)Ks[0] + (t + 768) * 16);
    if (t < 96) gload16(vp + voff[3], (char*)VT[0] + (t + 768) * 16);
  }
  __syncthreads();

  for (int kt = 0; kt < 16; ++kt) {
    const int cur = kt & 1;
    if (kt < 15) {
      const int nb = cur ^ 1;
      const short* kp = kbase + (kt + 1) * 64 * 96;
      const short* vp = vbase + (kt + 1) * 64;
#pragma unroll
      for (int i = 0; i < 3; ++i) {
        gload16(kp + koff[i], (char*)Ks[nb] + (t + i * 256) * 16);
        gload16(vp + voff[i], (char*)VT[nb] + (t + i * 256) * 16);
      }
      if (t < 64) gload16(kp + koff[3], (char*)Ks[nb] + (t + 768) * 16);
      if (t < 96) gload16(vp + voff[3], (char*)VT[nb] + (t + 768) * 16);
    }

    f32x16 s0 = {}, s1 = {};
    __builtin_amdgcn_s_setprio(1);
#pragma unroll
    for (int dm = 0; dm < 5; ++dm) {
      bf16x8 kf0 = *(const bf16x8*)&Ks[cur][l31 * KSS + dm * 16 + hi * 8];
      bf16x8 kf1 = *(const bf16x8*)&Ks[cur][(32 + l31) * KSS + dm * 16 + hi * 8];
      s0 = __builtin_amdgcn_mfma_f32_32x32x16_bf16(kf0, qf[dm], s0, 0, 0, 0);
      s1 = __builtin_amdgcn_mfma_f32_32x32x16_bf16(kf1, qf[dm], s1, 0, 0, 0);
    }
    __builtin_amdgcn_s_setprio(0);

    float pmax = s0[0];
#pragma unroll
    for (int r = 1; r < 16; ++r) pmax = fmaxf(pmax, s0[r]);
#pragma unroll
    for (int r = 0; r < 16; ++r) pmax = fmaxf(pmax, s1[r]);
    pmax = fmaxf(pmax, __shfl_xor(pmax, 32));

    if (__any(pmax > Mrun + 8.0f)) {
      float mn = fmaxf(Mrun, pmax);
      float corr = exp2f(Mrun - mn);
      Mrun = mn;
#pragma unroll
      for (int r = 0; r < 16; ++r) {
        int qr = (r & 3) + 8 * (r >> 2) + 4 * hi;
        float cr = __shfl(corr, qr);
        acc0[r] *= cr; acc1[r] *= cr; acc2[r] *= cr;
      }
    }

    unsigned int pk0[8], pk1[8];
#pragma unroll
    for (int b = 0; b < 4; ++b)
#pragma unroll
      for (int i = 0; i < 2; ++i) {
        pk0[b * 2 + i] = pk2(exp2f(s0[b * 4 + 2 * i] - Mrun), exp2f(s0[b * 4 + 2 * i + 1] - Mrun));
        pk1[b * 2 + i] = pk2(exp2f(s1[b * 4 + 2 * i] - Mrun), exp2f(s1[b * 4 + 2 * i + 1] - Mrun));
      }

    __builtin_amdgcn_s_setprio(1);
#pragma unroll
    for (int ks = 0; ks < 4; ++ks) {
      const int k1 = ks & 1;
      unsigned int A0, A1, B0, B1;
      if (ks < 2) { A0 = pk0[4 * k1]; A1 = pk0[4 * k1 + 1]; B0 = pk0[4 * k1 + 2]; B1 = pk0[4 * k1 + 3]; }
      else        { A0 = pk1[4 * k1]; A1 = pk1[4 * k1 + 1]; B0 = pk1[4 * k1 + 2]; B1 = pk1[4 * k1 + 3]; }
      unsigned int SA0 = __shfl_xor((int)A0, 32), SA1 = __shfl_xor((int)A1, 32);
      unsigned int SB0 = __shfl_xor((int)B0, 32), SB1 = __shfl_xor((int)B1, 32);
      u32x4 wv;
      wv.x = hi ? SB0 : A0;
      wv.y = hi ? SB1 : A1;
      wv.z = hi ? B0 : SA0;
      wv.w = hi ? B1 : SA1;
      bf16x8 af = __builtin_bit_cast(bf16x8, wv);
      bf16x8 vf0 = *(const bf16x8*)&VT[cur][l31 * VTS + ks * 16 + hi * 8];
      bf16x8 vf1 = *(const bf16x8*)&VT[cur][(32 + l31) * VTS + ks * 16 + hi * 8];
      bf16x8 vf2 = *(const bf16x8*)&VT[cur][(64 + l31) * VTS + ks * 16 + hi * 8];
      acc0 = __builtin_amdgcn_mfma_f32_32x32x16_bf16(af, vf0, acc0, 0, 0, 0);
      acc1 = __builtin_amdgcn_mfma_f32_32x32x16_bf16(af, vf1, acc1, 0, 0, 0);
      acc2 = __builtin_amdgcn_mfma_f32_32x32x16_bf16(af, vf2, acc2, 0, 0, 0);
    }
    __builtin_amdgcn_s_setprio(0);

    __syncthreads();
  }

#pragma unroll
  for (int r = 0; r < 16; ++r) {
    float l = __shfl(acc2[r], (lane & 32) | 8);
    float inv = 1.0f / l;
    int q = q0 + (r & 3) + 8 * (r >> 2) + 4 * hi;
    size_t base = (size_t)(seg * 1024 + q) * 1152 + head * 72;
    Og[base + l31]      = f2b(acc0[r] * inv);
    Og[base + 32 + l31] = f2b(acc1[r] * inv);
    if (l31 < 8) Og[base + 64 + l31] = f2b(acc2[r] * inv);
  }
}

// ---------------- launch ----------------
extern "C" void kernel_launch(void* const* d_in, const int* in_sizes, int n_in,
                              void* d_out, int out_size, void* d_ws, size_t ws_size,
                              hipStream_t stream) {
  (void)in_sizes; (void)n_in; (void)out_size; (void)ws_size;
  const float* x      = (const float*)d_in[0];
  const float* cosb   = (const float*)d_in[1];
  const float* sinb   = (const float*)d_in[2];
  const float* qkv_w  = (const float*)d_in[3];
  const float* qkv_b  = (const float*)d_in[4];
  const float* proj_w = (const float*)d_in[5];
  const float* proj_b = (const float*)d_in[6];

  char* ws = (char*)d_ws;
  size_t o = 0;
  short* xb  = (short*)(ws + o); o += (size_t)SS * EE * 2;
  short* qwb = (short*)(ws + o); o += (size_t)E3 * EE * 2;
  short* pwb = (short*)(ws + o); o += (size_t)EE * EE * 2;
  short* qkv = (short*)(ws + o); o += (size_t)SS * E3 * 2;
  short* Qg  = (short*)(ws + o); o += (size_t)SEGN * HH * LSEG * DP * 2;
  short* Kg  = (short*)(ws + o); o += (size_t)SEGN * HH * LSEG * DP * 2;
  short* Vg  = (short*)(ws + o); o += (size_t)SEGN * HH * DP * LSEG * 2;
  short* og  = xb; // x dead after GEMM1

  k_cvt<<<2048, 256, 0, stream>>>(x, xb, SS * EE / 4);
  k_cvt<<<1024, 256, 0, stream>>>(qkv_w, qwb, E3 * EE / 4);
  k_cvt<<<512, 256, 0, stream>>>(proj_w, pwb, EE * EE / 4);

  dim3 g1(SS / 128, E3 / 128);    // 64 x 27 = 1728 blocks, 2/CU co-resident
  k_gemm128<1><<<g1, 256, 0, stream>>>(xb, qwb, qkv_b, qkv, EE, E3);

  k_rope<<<SEGN * HH * 16, 256, 0, stream>>>(qkv, cosb, sinb, Qg, Kg, Vg);

  k_attn<<<SEGN * HH * 8, 256, 0, stream>>>(Qg, Kg, Vg, og);

  dim3 g2(SS / 128, EE / 128);    // 64 x 9 = 576 blocks
  k_gemm128<0><<<g2, 256, 0, stream>>>(og, pwb, proj_b, d_out, EE, EE);
}

// Round 13
// 254.895 us; speedup vs baseline: 1.0692x; 1.0692x over previous
//
#include <hip/hip_runtime.h>
#include <hip/hip_bf16.h>
#include <stdint.h>

#define SEGN 8
#define LSEG 1024
#define SS   8192
#define EE   1152
#define HH   16
#define DD   72
#define DP   96
#define E3   3456

typedef __attribute__((ext_vector_type(8)))  __bf16 bf16x8;
typedef __attribute__((ext_vector_type(4)))  float  f32x4;
typedef __attribute__((ext_vector_type(16))) float  f32x16;
typedef __attribute__((ext_vector_type(4)))  unsigned int u32x4;

__device__ __forceinline__ short f2b(float x) {
  __hip_bfloat16 h = __float2bfloat16(x);
  return __builtin_bit_cast(short, h);
}
__device__ __forceinline__ float b2f(short x) {
  return __bfloat162float(__builtin_bit_cast(__hip_bfloat16, x));
}
__device__ __forceinline__ unsigned int pk2(float x, float y) {
  return (unsigned int)(unsigned short)f2b(x) |
         ((unsigned int)(unsigned short)f2b(y) << 16);
}
__device__ __forceinline__ void gload16(const void* g, void* l) {
  __builtin_amdgcn_global_load_lds(
      (const __attribute__((address_space(1))) unsigned int*)g,
      (__attribute__((address_space(3))) unsigned int*)l, 16, 0, 0);
}

#define BAR() __builtin_amdgcn_s_barrier()

// ---------------- fp32 -> bf16 convert ----------------
__global__ void k_cvt(const float* __restrict__ in, short* __restrict__ out, int n4) {
  int i = blockIdx.x * blockDim.x + threadIdx.x;
  int stride = gridDim.x * blockDim.x;
  for (; i < n4; i += stride) {
    float4 v = reinterpret_cast<const float4*>(in)[i];
    short4 o;
    o.x = f2b(v.x); o.y = f2b(v.y); o.z = f2b(v.z); o.w = f2b(v.w);
    reinterpret_cast<short4*>(out)[i] = o;
  }
}

// ---------------- 128x128 dbuf GEMM, 32KB LDS -> 4 blocks/CU ----------------
// 256 thr = 4 waves (2m x 2n), wave tile 64x64, acc[4][4], BK=32, NT=K/32.
// LDS [2 bufs][128 rows][32 shorts] per side = 32KB total.
// Staging (R11-proven): chunk c -> row c>>2, slot c&3; logical slot ^= (row>>1)&3
//   on the GLOBAL source (LDS dest linear); 4 consecutive lanes = one 64B line.
// Read (R11-proven): byte = row*64 + ((kg ^ ((r16>>1)&3))<<4) -> conflict-free b128.
// Per tile t: vmcnt(0) [exactly tile t's 4 loads, issued one tile ago] ->
//   s_barrier -> sched_barrier -> STAGE(t+1, buf^1) -> ds_read + 16 MFMA.
// Race-free: buf^1's readers (tile t-1) finished before this tile's barrier.
// Occupancy is the lever: 4 blocks/CU (16 waves) absorb barrier/wait stalls.
template <int OUT_BF16>
__global__ __launch_bounds__(256, 4) void k_gemm128(
    const short* __restrict__ A, const short* __restrict__ B,
    const float* __restrict__ bias, void* __restrict__ Cout,
    int K, int N)
{
  __shared__ __align__(16) short Als[2][128 * 32];
  __shared__ __align__(16) short Bls[2][128 * 32];
  const int t = threadIdx.x;
  const int lane = t & 63, w = t >> 6;
  const int r16 = lane & 15, kg = lane >> 4;
  const int wm = w >> 1, wn = w & 1;
  const int m0 = blockIdx.x * 128, n0 = blockIdx.y * 128;
  const int NT = K >> 5;

  // staging sources (consecutive-lane coalesced, inverse-swizzled slot)
  const short* pa[2];
  const short* pb[2];
#pragma unroll
  for (int g = 0; g < 2; ++g) {
    int c = t + g * 256;
    int row = c >> 2;
    int sl = (c & 3) ^ ((row >> 1) & 3);
    pa[g] = A + (size_t)(m0 + row) * K + sl * 8;
    pb[g] = B + (size_t)(n0 + row) * K + sl * 8;
  }

#define STAGE(buf, kt_) do { \
    _Pragma("unroll") \
    for (int g = 0; g < 2; ++g) { \
      gload16(pa[g] + (kt_) * 32, (char*)Als[buf] + (t + g * 256) * 16); \
      gload16(pb[g] + (kt_) * 32, (char*)Bls[buf] + (t + g * 256) * 16); \
    } } while (0)

  // swizzled read bases: frag row = w?*64 + mi*16 + r16; (row>>1)&3 == (r16>>1)&3
  const int xorv = (kg ^ ((r16 >> 1) & 3)) << 4;
  const int aoff = (wm * 64 + r16) * 64 + xorv;
  const int boff = (wn * 64 + r16) * 64 + xorv;

  f32x4 acc[4][4] = {};

  // prologue: tile 0 in flight
  STAGE(0, 0);

  for (int kt = 0; kt < NT; ++kt) {
    const int cur = kt & 1;
    asm volatile("s_waitcnt vmcnt(0)" ::: "memory");  // tile kt's loads landed
    BAR();
    __builtin_amdgcn_sched_barrier(0);  // keep ds_reads below the barrier

    // prefetch next tile into the other buffer (its readers finished pre-barrier)
    if (kt + 1 < NT) STAGE(cur ^ 1, kt + 1);

    const char* Ab = (const char*)Als[cur] + aoff;
    const char* Bb = (const char*)Bls[cur] + boff;
    bf16x8 a_[4], b_[4];
#pragma unroll
    for (int i = 0; i < 4; ++i) {
      a_[i] = *(const bf16x8*)(Ab + i * 1024);
      b_[i] = *(const bf16x8*)(Bb + i * 1024);
    }
    __builtin_amdgcn_s_setprio(1);
#pragma unroll
    for (int mi = 0; mi < 4; ++mi)
#pragma unroll
      for (int ni = 0; ni < 4; ++ni)
        acc[mi][ni] = __builtin_amdgcn_mfma_f32_16x16x32_bf16(a_[mi], b_[ni], acc[mi][ni], 0, 0, 0);
    __builtin_amdgcn_s_setprio(0);
  }
#undef STAGE

  // epilogue
#pragma unroll
  for (int ni = 0; ni < 4; ++ni) {
    int col = n0 + wn * 64 + ni * 16 + r16;
    float bv = bias[col];
#pragma unroll
    for (int mi = 0; mi < 4; ++mi)
#pragma unroll
      for (int r = 0; r < 4; ++r) {
        int row = m0 + wm * 64 + mi * 16 + kg * 4 + r;
        float v = acc[mi][ni][r] + bv;
        if (OUT_BF16) ((short*)Cout)[(size_t)row * N + col] = f2b(v);
        else          ((float*)Cout)[(size_t)row * N + col] = v;
      }
  }
}

// ---------------- RoPE + Q/K/V repack ----------------
__global__ __launch_bounds__(256) void k_rope(
    const short* __restrict__ qkv, const float* __restrict__ cosb, const float* __restrict__ sinb,
    short* __restrict__ Qg, short* __restrict__ Kg, short* __restrict__ Vg)
{
  __shared__ short vt[72][64];
  const int b = blockIdx.x;
  const int seg = b >> 8, head = (b >> 4) & 15, pb = b & 15;
  const int pos0 = pb * 64;
  const int t = threadIdx.x;
  const int sh = seg * 16 + head;
  const float qscale = 0.17002540410995343f; // log2(e)/sqrt(72)

#pragma unroll
  for (int i = 0; i < 24; ++i) {
    int e = t + i * 256;
    int p = e / 96, d = e % 96;
    int s = seg * 1024 + pos0 + p;
    int ob = (sh * 1024 + pos0 + p) * 96 + d;
    short qo = 0, ko = 0;
    if (d < 72) {
      int base = s * E3 + head * 72;
      float c = cosb[s * 72 + d], sn = sinb[s * 72 + d];
      int d2 = d < 36 ? d + 36 : d - 36;
      float sgn = d < 36 ? -1.f : 1.f;
      float q1 = b2f(qkv[base + d]),        q2 = b2f(qkv[base + d2]);
      float k1 = b2f(qkv[base + 1152 + d]), k2 = b2f(qkv[base + 1152 + d2]);
      qo = f2b((q1 * c + sgn * q2 * sn) * qscale);
      ko = f2b(k1 * c + sgn * k2 * sn);
    }
    Qg[ob] = qo;
    Kg[ob] = ko;
  }
  for (int i = 0; i < 18; ++i) {
    int e = t + i * 256;
    int p = e / 72, d = e % 72;
    int s = seg * 1024 + pos0 + p;
    vt[d][p] = qkv[s * E3 + 2304 + head * 72 + d];
  }
  __syncthreads();
#pragma unroll
  for (int i = 0; i < 24; ++i) {
    int e = t + i * 256;
    int d = e >> 6, p = e & 63;
    short v;
    if (d < 72)       v = vt[d][p];
    else if (d == 72) v = (short)0x3F80;  // bf16 1.0 -> denominator column
    else              v = 0;
    Vg[(sh * 96 + d) * 1024 + pos0 + p] = v;
  }
}

// ---------------- Flash attention: swapped-QK 32x32, double-buffered async staging ----
#define KSS 104
#define VTS 72
__global__ __launch_bounds__(256, 2) void k_attn(
    const short* __restrict__ Qg, const short* __restrict__ Kg, const short* __restrict__ Vg,
    short* __restrict__ Og)
{
  __shared__ __align__(16) short Ks[2][64 * KSS];
  __shared__ __align__(16) short VT[2][96 * VTS];
  const int p_ = blockIdx.x;
  const int xcd = p_ & 7, rest = p_ >> 3;
  const int qb = rest & 7, shi = rest >> 3;
  const int sh = xcd * 16 + shi;
  const int seg = sh >> 4, head = sh & 15;
  const int t = threadIdx.x, lane = t & 63, wave = t >> 6;
  const int l31 = lane & 31, hi = lane >> 5;
  const int q0 = qb * 128 + wave * 32;

  bf16x8 qf[5];
  {
    const short* qp = Qg + ((size_t)(sh * 1024 + q0 + l31)) * 96 + hi * 8;
#pragma unroll
    for (int dm = 0; dm < 5; ++dm) qf[dm] = *(const bf16x8*)(qp + dm * 16);
  }

  const short* kbase = Kg + (size_t)sh * 1024 * 96;
  const short* vbase = Vg + (size_t)sh * 96 * 1024;
  int koff[4], voff[4];
#pragma unroll
  for (int i = 0; i < 4; ++i) {
    int c = t + i * 256;
    int kr = c / 13, kc8 = c - kr * 13;
    koff[i] = kr * 96 + ((kc8 == 12) ? 0 : kc8 * 8);
    int vr = c / 9, vc8 = c - vr * 9;
    voff[i] = vr * 1024 + ((vc8 == 8) ? 0 : vc8 * 8);
  }

  f32x16 acc0 = {}, acc1 = {}, acc2 = {};
  float Mrun = -1e30f;

  {
    const short* kp = kbase;
    const short* vp = vbase;
#pragma unroll
    for (int i = 0; i < 3; ++i) {
      gload16(kp + koff[i], (char*)Ks[0] + (t + i * 256) * 16);
      gload16(vp + voff[i], (char*)VT[0] + (t + i * 256) * 16);
    }
    if (t < 64) gload16(kp + koff[3], (char*)Ks[0] + (t + 768) * 16);
    if (t < 96) gload16(vp + voff[3], (char*)VT[0] + (t + 768) * 16);
  }
  __syncthreads();

  for (int kt = 0; kt < 16; ++kt) {
    const int cur = kt & 1;
    if (kt < 15) {
      const int nb = cur ^ 1;
      const short* kp = kbase + (kt + 1) * 64 * 96;
      const short* vp = vbase + (kt + 1) * 64;
#pragma unroll
      for (int i = 0; i < 3; ++i) {
        gload16(kp + koff[i], (char*)Ks[nb] + (t + i * 256) * 16);
        gload16(vp + voff[i], (char*)VT[nb] + (t + i * 256) * 16);
      }
      if (t < 64) gload16(kp + koff[3], (char*)Ks[nb] + (t + 768) * 16);
      if (t < 96) gload16(vp + voff[3], (char*)VT[nb] + (t + 768) * 16);
    }

    f32x16 s0 = {}, s1 = {};
    __builtin_amdgcn_s_setprio(1);
#pragma unroll
    for (int dm = 0; dm < 5; ++dm) {
      bf16x8 kf0 = *(const bf16x8*)&Ks[cur][l31 * KSS + dm * 16 + hi * 8];
      bf16x8 kf1 = *(const bf16x8*)&Ks[cur][(32 + l31) * KSS + dm * 16 + hi * 8];
      s0 = __builtin_amdgcn_mfma_f32_32x32x16_bf16(kf0, qf[dm], s0, 0, 0, 0);
      s1 = __builtin_amdgcn_mfma_f32_32x32x16_bf16(kf1, qf[dm], s1, 0, 0, 0);
    }
    __builtin_amdgcn_s_setprio(0);

    float pmax = s0[0];
#pragma unroll
    for (int r = 1; r < 16; ++r) pmax = fmaxf(pmax, s0[r]);
#pragma unroll
    for (int r = 0; r < 16; ++r) pmax = fmaxf(pmax, s1[r]);
    pmax = fmaxf(pmax, __shfl_xor(pmax, 32));

    if (__any(pmax > Mrun + 8.0f)) {
      float mn = fmaxf(Mrun, pmax);
      float corr = exp2f(Mrun - mn);
      Mrun = mn;
#pragma unroll
      for (int r = 0; r < 16; ++r) {
        int qr = (r & 3) + 8 * (r >> 2) + 4 * hi;
        float cr = __shfl(corr, qr);
        acc0[r] *= cr; acc1[r] *= cr; acc2[r] *= cr;
      }
    }

    unsigned int pk0[8], pk1[8];
#pragma unroll
    for (int b = 0; b < 4; ++b)
#pragma unroll
      for (int i = 0; i < 2; ++i) {
        pk0[b * 2 + i] = pk2(exp2f(s0[b * 4 + 2 * i] - Mrun), exp2f(s0[b * 4 + 2 * i + 1] - Mrun));
        pk1[b * 2 + i] = pk2(exp2f(s1[b * 4 + 2 * i] - Mrun), exp2f(s1[b * 4 + 2 * i + 1] - Mrun));
      }

    __builtin_amdgcn_s_setprio(1);
#pragma unroll
    for (int ks = 0; ks < 4; ++ks) {
      const int k1 = ks & 1;
      unsigned int A0, A1, B0, B1;
      if (ks < 2) { A0 = pk0[4 * k1]; A1 = pk0[4 * k1 + 1]; B0 = pk0[4 * k1 + 2]; B1 = pk0[4 * k1 + 3]; }
      else        { A0 = pk1[4 * k1]; A1 = pk1[4 * k1 + 1]; B0 = pk1[4 * k1 + 2]; B1 = pk1[4 * k1 + 3]; }
      unsigned int SA0 = __shfl_xor((int)A0, 32), SA1 = __shfl_xor((int)A1, 32);
      unsigned int SB0 = __shfl_xor((int)B0, 32), SB1 = __shfl_xor((int)B1, 32);
      u32x4 wv;
      wv.x = hi ? SB0 : A0;
      wv.y = hi ? SB1 : A1;
      wv.z = hi ? B0 : SA0;
      wv.w = hi ? B1 : SA1;
      bf16x8 af = __builtin_bit_cast(bf16x8, wv);
      bf16x8 vf0 = *(const bf16x8*)&VT[cur][l31 * VTS + ks * 16 + hi * 8];
      bf16x8 vf1 = *(const bf16x8*)&VT[cur][(32 + l31) * VTS + ks * 16 + hi * 8];
      bf16x8 vf2 = *(const bf16x8*)&VT[cur][(64 + l31) * VTS + ks * 16 + hi * 8];
      acc0 = __builtin_amdgcn_mfma_f32_32x32x16_bf16(af, vf0, acc0, 0, 0, 0);
      acc1 = __builtin_amdgcn_mfma_f32_32x32x16_bf16(af, vf1, acc1, 0, 0, 0);
      acc2 = __builtin_amdgcn_mfma_f32_32x32x16_bf16(af, vf2, acc2, 0, 0, 0);
    }
    __builtin_amdgcn_s_setprio(0);

    __syncthreads();
  }

#pragma unroll
  for (int r = 0; r < 16; ++r) {
    float l = __shfl(acc2[r], (lane & 32) | 8);
    float inv = 1.0f / l;
    int q = q0 + (r & 3) + 8 * (r >> 2) + 4 * hi;
    size_t base = (size_t)(seg * 1024 + q) * 1152 + head * 72;
    Og[base + l31]      = f2b(acc0[r] * inv);
    Og[base + 32 + l31] = f2b(acc1[r] * inv);
    if (l31 < 8) Og[base + 64 + l31] = f2b(acc2[r] * inv);
  }
}

// ---------------- launch ----------------
extern "C" void kernel_launch(void* const* d_in, const int* in_sizes, int n_in,
                              void* d_out, int out_size, void* d_ws, size_t ws_size,
                              hipStream_t stream) {
  (void)in_sizes; (void)n_in; (void)out_size; (void)ws_size;
  const float* x      = (const float*)d_in[0];
  const float* cosb   = (const float*)d_in[1];
  const float* sinb   = (const float*)d_in[2];
  const float* qkv_w  = (const float*)d_in[3];
  const float* qkv_b  = (const float*)d_in[4];
  const float* proj_w = (const float*)d_in[5];
  const float* proj_b = (const float*)d_in[6];

  char* ws = (char*)d_ws;
  size_t o = 0;
  short* xb  = (short*)(ws + o); o += (size_t)SS * EE * 2;
  short* qwb = (short*)(ws + o); o += (size_t)E3 * EE * 2;
  short* pwb = (short*)(ws + o); o += (size_t)EE * EE * 2;
  short* qkv = (short*)(ws + o); o += (size_t)SS * E3 * 2;
  short* Qg  = (short*)(ws + o); o += (size_t)SEGN * HH * LSEG * DP * 2;
  short* Kg  = (short*)(ws + o); o += (size_t)SEGN * HH * LSEG * DP * 2;
  short* Vg  = (short*)(ws + o); o += (size_t)SEGN * HH * DP * LSEG * 2;
  short* og  = xb; // x dead after GEMM1

  k_cvt<<<2048, 256, 0, stream>>>(x, xb, SS * EE / 4);
  k_cvt<<<1024, 256, 0, stream>>>(qkv_w, qwb, E3 * EE / 4);
  k_cvt<<<512, 256, 0, stream>>>(proj_w, pwb, EE * EE / 4);

  dim3 g1(SS / 128, E3 / 128);    // 64 x 27 = 1728 blocks, 4/CU co-resident
  k_gemm128<1><<<g1, 256, 0, stream>>>(xb, qwb, qkv_b, qkv, EE, E3);

  k_rope<<<SEGN * HH * 16, 256, 0, stream>>>(qkv, cosb, sinb, Qg, Kg, Vg);

  k_attn<<<SEGN * HH * 8, 256, 0, stream>>>(Qg, Kg, Vg, og);

  dim3 g2(SS / 128, EE / 128);    // 64 x 9 = 576 blocks
  k_gemm128<0><<<g2, 256, 0, stream>>>(og, pwb, proj_b, d_out, EE, EE);
}

// Round 14
// 248.994 us; speedup vs baseline: 1.0945x; 1.0237x over previous
//
#include <hip/hip_runtime.h>
#include <hip/hip_bf16.h>
#include <stdint.h>

#define SEGN 8
#define LSEG 1024
#define SS   8192
#define EE   1152
#define HH   16
#define DD   72
#define DP   96
#define E3   3456

typedef __attribute__((ext_vector_type(8)))  __bf16 bf16x8;
typedef __attribute__((ext_vector_type(4)))  float  f32x4;
typedef __attribute__((ext_vector_type(16))) float  f32x16;
typedef __attribute__((ext_vector_type(4)))  unsigned int u32x4;

__device__ __forceinline__ short f2b(float x) {
  __hip_bfloat16 h = __float2bfloat16(x);
  return __builtin_bit_cast(short, h);
}
__device__ __forceinline__ float b2f(short x) {
  return __bfloat162float(__builtin_bit_cast(__hip_bfloat16, x));
}
__device__ __forceinline__ unsigned int pk2(float x, float y) {
  return (unsigned int)(unsigned short)f2b(x) |
         ((unsigned int)(unsigned short)f2b(y) << 16);
}
__device__ __forceinline__ void gload16(const void* g, void* l) {
  __builtin_amdgcn_global_load_lds(
      (const __attribute__((address_space(1))) unsigned int*)g,
      (__attribute__((address_space(3))) unsigned int*)l, 16, 0, 0);
}

#define BAR() __builtin_amdgcn_s_barrier()

// ---------------- fp32 -> bf16 convert ----------------
__global__ void k_cvt(const float* __restrict__ in, short* __restrict__ out, int n4) {
  int i = blockIdx.x * blockDim.x + threadIdx.x;
  int stride = gridDim.x * blockDim.x;
  for (; i < n4; i += stride) {
    float4 v = reinterpret_cast<const float4*>(in)[i];
    short4 o;
    o.x = f2b(v.x); o.y = f2b(v.y); o.z = f2b(v.z); o.w = f2b(v.w);
    reinterpret_cast<short4*>(out)[i] = o;
  }
}

// ---------------- 128x128 dbuf GEMM, 32KB LDS (R13, frozen) ----------------
template <int OUT_BF16>
__global__ __launch_bounds__(256, 4) void k_gemm128(
    const short* __restrict__ A, const short* __restrict__ B,
    const float* __restrict__ bias, void* __restrict__ Cout,
    int K, int N)
{
  __shared__ __align__(16) short Als[2][128 * 32];
  __shared__ __align__(16) short Bls[2][128 * 32];
  const int t = threadIdx.x;
  const int lane = t & 63, w = t >> 6;
  const int r16 = lane & 15, kg = lane >> 4;
  const int wm = w >> 1, wn = w & 1;
  const int m0 = blockIdx.x * 128, n0 = blockIdx.y * 128;
  const int NT = K >> 5;

  const short* pa[2];
  const short* pb[2];
#pragma unroll
  for (int g = 0; g < 2; ++g) {
    int c = t + g * 256;
    int row = c >> 2;
    int sl = (c & 3) ^ ((row >> 1) & 3);
    pa[g] = A + (size_t)(m0 + row) * K + sl * 8;
    pb[g] = B + (size_t)(n0 + row) * K + sl * 8;
  }

#define STAGE(buf, kt_) do { \
    _Pragma("unroll") \
    for (int g = 0; g < 2; ++g) { \
      gload16(pa[g] + (kt_) * 32, (char*)Als[buf] + (t + g * 256) * 16); \
      gload16(pb[g] + (kt_) * 32, (char*)Bls[buf] + (t + g * 256) * 16); \
    } } while (0)

  const int xorv = (kg ^ ((r16 >> 1) & 3)) << 4;
  const int aoff = (wm * 64 + r16) * 64 + xorv;
  const int boff = (wn * 64 + r16) * 64 + xorv;

  f32x4 acc[4][4] = {};

  STAGE(0, 0);

  for (int kt = 0; kt < NT; ++kt) {
    const int cur = kt & 1;
    asm volatile("s_waitcnt vmcnt(0)" ::: "memory");
    BAR();
    __builtin_amdgcn_sched_barrier(0);

    if (kt + 1 < NT) STAGE(cur ^ 1, kt + 1);

    const char* Ab = (const char*)Als[cur] + aoff;
    const char* Bb = (const char*)Bls[cur] + boff;
    bf16x8 a_[4], b_[4];
#pragma unroll
    for (int i = 0; i < 4; ++i) {
      a_[i] = *(const bf16x8*)(Ab + i * 1024);
      b_[i] = *(const bf16x8*)(Bb + i * 1024);
    }
    __builtin_amdgcn_s_setprio(1);
#pragma unroll
    for (int mi = 0; mi < 4; ++mi)
#pragma unroll
      for (int ni = 0; ni < 4; ++ni)
        acc[mi][ni] = __builtin_amdgcn_mfma_f32_16x16x32_bf16(a_[mi], b_[ni], acc[mi][ni], 0, 0, 0);
    __builtin_amdgcn_s_setprio(0);
  }
#undef STAGE

#pragma unroll
  for (int ni = 0; ni < 4; ++ni) {
    int col = n0 + wn * 64 + ni * 16 + r16;
    float bv = bias[col];
#pragma unroll
    for (int mi = 0; mi < 4; ++mi)
#pragma unroll
      for (int r = 0; r < 4; ++r) {
        int row = m0 + wm * 64 + mi * 16 + kg * 4 + r;
        float v = acc[mi][ni][r] + bv;
        if (OUT_BF16) ((short*)Cout)[(size_t)row * N + col] = f2b(v);
        else          ((float*)Cout)[(size_t)row * N + col] = v;
      }
  }
}

// ---------------- RoPE + Q/K/V repack ----------------
__global__ __launch_bounds__(256) void k_rope(
    const short* __restrict__ qkv, const float* __restrict__ cosb, const float* __restrict__ sinb,
    short* __restrict__ Qg, short* __restrict__ Kg, short* __restrict__ Vg)
{
  __shared__ short vt[72][64];
  const int b = blockIdx.x;
  const int seg = b >> 8, head = (b >> 4) & 15, pb = b & 15;
  const int pos0 = pb * 64;
  const int t = threadIdx.x;
  const int sh = seg * 16 + head;
  const float qscale = 0.17002540410995343f; // log2(e)/sqrt(72)

#pragma unroll
  for (int i = 0; i < 24; ++i) {
    int e = t + i * 256;
    int p = e / 96, d = e % 96;
    int s = seg * 1024 + pos0 + p;
    int ob = (sh * 1024 + pos0 + p) * 96 + d;
    short qo = 0, ko = 0;
    if (d < 72) {
      int base = s * E3 + head * 72;
      float c = cosb[s * 72 + d], sn = sinb[s * 72 + d];
      int d2 = d < 36 ? d + 36 : d - 36;
      float sgn = d < 36 ? -1.f : 1.f;
      float q1 = b2f(qkv[base + d]),        q2 = b2f(qkv[base + d2]);
      float k1 = b2f(qkv[base + 1152 + d]), k2 = b2f(qkv[base + 1152 + d2]);
      qo = f2b((q1 * c + sgn * q2 * sn) * qscale);
      ko = f2b(k1 * c + sgn * k2 * sn);
    }
    Qg[ob] = qo;
    Kg[ob] = ko;
  }
  for (int i = 0; i < 18; ++i) {
    int e = t + i * 256;
    int p = e / 72, d = e % 72;
    int s = seg * 1024 + pos0 + p;
    vt[d][p] = qkv[s * E3 + 2304 + head * 72 + d];
  }
  __syncthreads();
#pragma unroll
  for (int i = 0; i < 24; ++i) {
    int e = t + i * 256;
    int d = e >> 6, p = e & 63;
    short v;
    if (d < 72)       v = vt[d][p];
    else if (d == 72) v = (short)0x3F80;  // bf16 1.0 -> denominator column
    else              v = 0;
    Vg[(sh * 96 + d) * 1024 + pos0 + p] = v;
  }
}

// ---------------- Flash attention: swapped-QK 32x32, dbuf staging ----------------
// R14: Ks stores only 80 d-cols (dm<5), stride 88 -> LDS 49KB -> 3 blocks/CU.
//      PV half-exchange via v_permlane32_swap_b32 (VALU pipe; replaces
//      4 shfl_xor + 4 cndmask per ks with 2 permlane ops).
#define KSS 88
#define VTS 72
__global__ __launch_bounds__(256, 3) void k_attn(
    const short* __restrict__ Qg, const short* __restrict__ Kg, const short* __restrict__ Vg,
    short* __restrict__ Og)
{
  __shared__ __align__(16) short Ks[2][64 * KSS];   // 11 chunks/row (10 data + 1 pad)
  __shared__ __align__(16) short VT[2][96 * VTS];   // 9 chunks/row (8 data + 1 pad)
  const int p_ = blockIdx.x;
  const int xcd = p_ & 7, rest = p_ >> 3;
  const int qb = rest & 7, shi = rest >> 3;
  const int sh = xcd * 16 + shi;
  const int seg = sh >> 4, head = sh & 15;
  const int t = threadIdx.x, lane = t & 63, wave = t >> 6;
  const int l31 = lane & 31, hi = lane >> 5;
  const int q0 = qb * 128 + wave * 32;

  bf16x8 qf[5];
  {
    const short* qp = Qg + ((size_t)(sh * 1024 + q0 + l31)) * 96 + hi * 8;
#pragma unroll
    for (int dm = 0; dm < 5; ++dm) qf[dm] = *(const bf16x8*)(qp + dm * 16);
  }

  const short* kbase = Kg + (size_t)sh * 1024 * 96;
  const short* vbase = Vg + (size_t)sh * 96 * 1024;
  int koff[3], voff[4];
#pragma unroll
  for (int i = 0; i < 3; ++i) {
    int c = t + i * 256;
    int kr = c / 11, kc8 = c - kr * 11;
    koff[i] = kr * 96 + ((kc8 == 10) ? 0 : kc8 * 8);
  }
#pragma unroll
  for (int i = 0; i < 4; ++i) {
    int c = t + i * 256;
    int vr = c / 9, vc8 = c - vr * 9;
    voff[i] = vr * 1024 + ((vc8 == 8) ? 0 : vc8 * 8);
  }

  // Ks: 64 rows x 11 chunks = 704; passes: 2 full + t<192.
  // VT: 96 rows x 9 chunks = 864; passes: 3 full + t<96.
#define STAGE_KV(buf, kt_) do { \
    const short* kp = kbase + (kt_) * 64 * 96; \
    const short* vp = vbase + (kt_) * 64; \
    _Pragma("unroll") \
    for (int i = 0; i < 2; ++i) { \
      gload16(kp + koff[i], (char*)Ks[buf] + (t + i * 256) * 16); \
      gload16(vp + voff[i], (char*)VT[buf] + (t + i * 256) * 16); \
    } \
    gload16(vp + voff[2], (char*)VT[buf] + (t + 512) * 16); \
    if (t < 192) gload16(kp + koff[2], (char*)Ks[buf] + (t + 512) * 16); \
    if (t < 96)  gload16(vp + voff[3], (char*)VT[buf] + (t + 768) * 16); \
  } while (0)

  f32x16 acc0 = {}, acc1 = {}, acc2 = {};
  float Mrun = -1e30f;

  STAGE_KV(0, 0);
  __syncthreads();

  for (int kt = 0; kt < 16; ++kt) {
    const int cur = kt & 1;
    if (kt < 15) STAGE_KV(cur ^ 1, kt + 1);

    f32x16 s0 = {}, s1 = {};
    __builtin_amdgcn_s_setprio(1);
#pragma unroll
    for (int dm = 0; dm < 5; ++dm) {
      bf16x8 kf0 = *(const bf16x8*)&Ks[cur][l31 * KSS + dm * 16 + hi * 8];
      bf16x8 kf1 = *(const bf16x8*)&Ks[cur][(32 + l31) * KSS + dm * 16 + hi * 8];
      s0 = __builtin_amdgcn_mfma_f32_32x32x16_bf16(kf0, qf[dm], s0, 0, 0, 0);
      s1 = __builtin_amdgcn_mfma_f32_32x32x16_bf16(kf1, qf[dm], s1, 0, 0, 0);
    }
    __builtin_amdgcn_s_setprio(0);

    float pmax = s0[0];
#pragma unroll
    for (int r = 1; r < 16; ++r) pmax = fmaxf(pmax, s0[r]);
#pragma unroll
    for (int r = 0; r < 16; ++r) pmax = fmaxf(pmax, s1[r]);
    pmax = fmaxf(pmax, __shfl_xor(pmax, 32));

    if (__any(pmax > Mrun + 8.0f)) {
      float mn = fmaxf(Mrun, pmax);
      float corr = exp2f(Mrun - mn);
      Mrun = mn;
#pragma unroll
      for (int r = 0; r < 16; ++r) {
        int qr = (r & 3) + 8 * (r >> 2) + 4 * hi;
        float cr = __shfl(corr, qr);
        acc0[r] *= cr; acc1[r] *= cr; acc2[r] *= cr;
      }
    }

    unsigned int pk0[8], pk1[8];
#pragma unroll
    for (int b = 0; b < 4; ++b)
#pragma unroll
      for (int i = 0; i < 2; ++i) {
        pk0[b * 2 + i] = pk2(exp2f(s0[b * 4 + 2 * i] - Mrun), exp2f(s0[b * 4 + 2 * i + 1] - Mrun));
        pk1[b * 2 + i] = pk2(exp2f(s1[b * 4 + 2 * i] - Mrun), exp2f(s1[b * 4 + 2 * i + 1] - Mrun));
      }

    __builtin_amdgcn_s_setprio(1);
#pragma unroll
    for (int ks = 0; ks < 4; ++ks) {
      const int k1 = ks & 1;
      unsigned int A0, A1, B0, B1;
      if (ks < 2) { A0 = pk0[4 * k1]; A1 = pk0[4 * k1 + 1]; B0 = pk0[4 * k1 + 2]; B1 = pk0[4 * k1 + 3]; }
      else        { A0 = pk1[4 * k1]; A1 = pk1[4 * k1 + 1]; B0 = pk1[4 * k1 + 2]; B1 = pk1[4 * k1 + 3]; }
      // row-swap: x = [A.row0|B.row0], z = [A.row1|B.row1]  (one VALU op each)
      unsigned int x0 = A0, z0 = B0, y0 = A1, w0 = B1;
      asm volatile("v_permlane32_swap_b32 %0, %1" : "+v"(x0), "+v"(z0));
      asm volatile("v_permlane32_swap_b32 %0, %1" : "+v"(y0), "+v"(w0));
      u32x4 wv;
      wv.x = x0; wv.y = y0; wv.z = z0; wv.w = w0;
      bf16x8 af = __builtin_bit_cast(bf16x8, wv);
      bf16x8 vf0 = *(const bf16x8*)&VT[cur][l31 * VTS + ks * 16 + hi * 8];
      bf16x8 vf1 = *(const bf16x8*)&VT[cur][(32 + l31) * VTS + ks * 16 + hi * 8];
      bf16x8 vf2 = *(const bf16x8*)&VT[cur][(64 + l31) * VTS + ks * 16 + hi * 8];
      acc0 = __builtin_amdgcn_mfma_f32_32x32x16_bf16(af, vf0, acc0, 0, 0, 0);
      acc1 = __builtin_amdgcn_mfma_f32_32x32x16_bf16(af, vf1, acc1, 0, 0, 0);
      acc2 = __builtin_amdgcn_mfma_f32_32x32x16_bf16(af, vf2, acc2, 0, 0, 0);
    }
    __builtin_amdgcn_s_setprio(0);

    __syncthreads();
  }
#undef STAGE_KV

#pragma unroll
  for (int r = 0; r < 16; ++r) {
    float l = __shfl(acc2[r], (lane & 32) | 8);
    float inv = 1.0f / l;
    int q = q0 + (r & 3) + 8 * (r >> 2) + 4 * hi;
    size_t base = (size_t)(seg * 1024 + q) * 1152 + head * 72;
    Og[base + l31]      = f2b(acc0[r] * inv);
    Og[base + 32 + l31] = f2b(acc1[r] * inv);
    if (l31 < 8) Og[base + 64 + l31] = f2b(acc2[r] * inv);
  }
}

// ---------------- launch ----------------
extern "C" void kernel_launch(void* const* d_in, const int* in_sizes, int n_in,
                              void* d_out, int out_size, void* d_ws, size_t ws_size,
                              hipStream_t stream) {
  (void)in_sizes; (void)n_in; (void)out_size; (void)ws_size;
  const float* x      = (const float*)d_in[0];
  const float* cosb   = (const float*)d_in[1];
  const float* sinb   = (const float*)d_in[2];
  const float* qkv_w  = (const float*)d_in[3];
  const float* qkv_b  = (const float*)d_in[4];
  const float* proj_w = (const float*)d_in[5];
  const float* proj_b = (const float*)d_in[6];

  char* ws = (char*)d_ws;
  size_t o = 0;
  short* xb  = (short*)(ws + o); o += (size_t)SS * EE * 2;
  short* qwb = (short*)(ws + o); o += (size_t)E3 * EE * 2;
  short* pwb = (short*)(ws + o); o += (size_t)EE * EE * 2;
  short* qkv = (short*)(ws + o); o += (size_t)SS * E3 * 2;
  short* Qg  = (short*)(ws + o); o += (size_t)SEGN * HH * LSEG * DP * 2;
  short* Kg  = (short*)(ws + o); o += (size_t)SEGN * HH * LSEG * DP * 2;
  short* Vg  = (short*)(ws + o); o += (size_t)SEGN * HH * DP * LSEG * 2;
  short* og  = xb; // x dead after GEMM1

  k_cvt<<<2048, 256, 0, stream>>>(x, xb, SS * EE / 4);
  k_cvt<<<1024, 256, 0, stream>>>(qkv_w, qwb, E3 * EE / 4);
  k_cvt<<<512, 256, 0, stream>>>(proj_w, pwb, EE * EE / 4);

  dim3 g1(SS / 128, E3 / 128);    // 64 x 27 = 1728 blocks, 4/CU co-resident
  k_gemm128<1><<<g1, 256, 0, stream>>>(xb, qwb, qkv_b, qkv, EE, E3);

  k_rope<<<SEGN * HH * 16, 256, 0, stream>>>(qkv, cosb, sinb, Qg, Kg, Vg);

  k_attn<<<SEGN * HH * 8, 256, 0, stream>>>(Qg, Kg, Vg, og);

  dim3 g2(SS / 128, EE / 128);    // 64 x 9 = 576 blocks
  k_gemm128<0><<<g2, 256, 0, stream>>>(og, pwb, proj_b, d_out, EE, EE);
}

// Round 15
// 248.207 us; speedup vs baseline: 1.0980x; 1.0032x over previous
//
#include <hip/hip_runtime.h>
#include <hip/hip_bf16.h>
#include <stdint.h>

#define SEGN 8
#define LSEG 1024
#define SS   8192
#define EE   1152
#define HH   16
#define DD   72
#define DP   96
#define E3   3456

typedef __attribute__((ext_vector_type(8)))  __bf16 bf16x8;
typedef __attribute__((ext_vector_type(4)))  float  f32x4;
typedef __attribute__((ext_vector_type(16))) float  f32x16;
typedef __attribute__((ext_vector_type(4)))  unsigned int u32x4;

__device__ __forceinline__ short f2b(float x) {
  __hip_bfloat16 h = __float2bfloat16(x);
  return __builtin_bit_cast(short, h);
}
__device__ __forceinline__ float b2f(short x) {
  return __bfloat162float(__builtin_bit_cast(__hip_bfloat16, x));
}
// HW packed f32->bf16 (RNE): dst.lo = bf16(lo), dst.hi = bf16(hi). 1 VALU op.
__device__ __forceinline__ unsigned int pkcvt(float lo, float hi) {
  unsigned int r;
  asm("v_cvt_pk_bf16_f32 %0, %1, %2" : "=v"(r) : "v"(lo), "v"(hi));
  return r;
}
__device__ __forceinline__ void gload16(const void* g, void* l) {
  __builtin_amdgcn_global_load_lds(
      (const __attribute__((address_space(1))) unsigned int*)g,
      (__attribute__((address_space(3))) unsigned int*)l, 16, 0, 0);
}

#define BAR() __builtin_amdgcn_s_barrier()

// ---------------- fp32 -> bf16 convert ----------------
__global__ void k_cvt(const float* __restrict__ in, short* __restrict__ out, int n4) {
  int i = blockIdx.x * blockDim.x + threadIdx.x;
  int stride = gridDim.x * blockDim.x;
  for (; i < n4; i += stride) {
    float4 v = reinterpret_cast<const float4*>(in)[i];
    short4 o;
    o.x = f2b(v.x); o.y = f2b(v.y); o.z = f2b(v.z); o.w = f2b(v.w);
    reinterpret_cast<short4*>(out)[i] = o;
  }
}

// ---------------- 128x128 dbuf GEMM, 32KB LDS (R13, frozen) ----------------
template <int OUT_BF16>
__global__ __launch_bounds__(256, 4) void k_gemm128(
    const short* __restrict__ A, const short* __restrict__ B,
    const float* __restrict__ bias, void* __restrict__ Cout,
    int K, int N)
{
  __shared__ __align__(16) short Als[2][128 * 32];
  __shared__ __align__(16) short Bls[2][128 * 32];
  const int t = threadIdx.x;
  const int lane = t & 63, w = t >> 6;
  const int r16 = lane & 15, kg = lane >> 4;
  const int wm = w >> 1, wn = w & 1;
  const int m0 = blockIdx.x * 128, n0 = blockIdx.y * 128;
  const int NT = K >> 5;

  const short* pa[2];
  const short* pb[2];
#pragma unroll
  for (int g = 0; g < 2; ++g) {
    int c = t + g * 256;
    int row = c >> 2;
    int sl = (c & 3) ^ ((row >> 1) & 3);
    pa[g] = A + (size_t)(m0 + row) * K + sl * 8;
    pb[g] = B + (size_t)(n0 + row) * K + sl * 8;
  }

#define STAGE(buf, kt_) do { \
    _Pragma("unroll") \
    for (int g = 0; g < 2; ++g) { \
      gload16(pa[g] + (kt_) * 32, (char*)Als[buf] + (t + g * 256) * 16); \
      gload16(pb[g] + (kt_) * 32, (char*)Bls[buf] + (t + g * 256) * 16); \
    } } while (0)

  const int xorv = (kg ^ ((r16 >> 1) & 3)) << 4;
  const int aoff = (wm * 64 + r16) * 64 + xorv;
  const int boff = (wn * 64 + r16) * 64 + xorv;

  f32x4 acc[4][4] = {};

  STAGE(0, 0);

  for (int kt = 0; kt < NT; ++kt) {
    const int cur = kt & 1;
    asm volatile("s_waitcnt vmcnt(0)" ::: "memory");
    BAR();
    __builtin_amdgcn_sched_barrier(0);

    if (kt + 1 < NT) STAGE(cur ^ 1, kt + 1);

    const char* Ab = (const char*)Als[cur] + aoff;
    const char* Bb = (const char*)Bls[cur] + boff;
    bf16x8 a_[4], b_[4];
#pragma unroll
    for (int i = 0; i < 4; ++i) {
      a_[i] = *(const bf16x8*)(Ab + i * 1024);
      b_[i] = *(const bf16x8*)(Bb + i * 1024);
    }
    __builtin_amdgcn_s_setprio(1);
#pragma unroll
    for (int mi = 0; mi < 4; ++mi)
#pragma unroll
      for (int ni = 0; ni < 4; ++ni)
        acc[mi][ni] = __builtin_amdgcn_mfma_f32_16x16x32_bf16(a_[mi], b_[ni], acc[mi][ni], 0, 0, 0);
    __builtin_amdgcn_s_setprio(0);
  }
#undef STAGE

#pragma unroll
  for (int ni = 0; ni < 4; ++ni) {
    int col = n0 + wn * 64 + ni * 16 + r16;
    float bv = bias[col];
#pragma unroll
    for (int mi = 0; mi < 4; ++mi)
#pragma unroll
      for (int r = 0; r < 4; ++r) {
        int row = m0 + wm * 64 + mi * 16 + kg * 4 + r;
        float v = acc[mi][ni][r] + bv;
        if (OUT_BF16) ((short*)Cout)[(size_t)row * N + col] = f2b(v);
        else          ((float*)Cout)[(size_t)row * N + col] = v;
      }
  }
}

// ---------------- RoPE + Q/K/V repack ----------------
__global__ __launch_bounds__(256) void k_rope(
    const short* __restrict__ qkv, const float* __restrict__ cosb, const float* __restrict__ sinb,
    short* __restrict__ Qg, short* __restrict__ Kg, short* __restrict__ Vg)
{
  __shared__ short vt[72][64];
  const int b = blockIdx.x;
  const int seg = b >> 8, head = (b >> 4) & 15, pb = b & 15;
  const int pos0 = pb * 64;
  const int t = threadIdx.x;
  const int sh = seg * 16 + head;
  const float qscale = 0.17002540410995343f; // log2(e)/sqrt(72)

#pragma unroll
  for (int i = 0; i < 24; ++i) {
    int e = t + i * 256;
    int p = e / 96, d = e % 96;
    int s = seg * 1024 + pos0 + p;
    int ob = (sh * 1024 + pos0 + p) * 96 + d;
    short qo = 0, ko = 0;
    if (d < 72) {
      int base = s * E3 + head * 72;
      float c = cosb[s * 72 + d], sn = sinb[s * 72 + d];
      int d2 = d < 36 ? d + 36 : d - 36;
      float sgn = d < 36 ? -1.f : 1.f;
      float q1 = b2f(qkv[base + d]),        q2 = b2f(qkv[base + d2]);
      float k1 = b2f(qkv[base + 1152 + d]), k2 = b2f(qkv[base + 1152 + d2]);
      qo = f2b((q1 * c + sgn * q2 * sn) * qscale);
      ko = f2b(k1 * c + sgn * k2 * sn);
    }
    Qg[ob] = qo;
    Kg[ob] = ko;
  }
  for (int i = 0; i < 18; ++i) {
    int e = t + i * 256;
    int p = e / 72, d = e % 72;
    int s = seg * 1024 + pos0 + p;
    vt[d][p] = qkv[s * E3 + 2304 + head * 72 + d];
  }
  __syncthreads();
#pragma unroll
  for (int i = 0; i < 24; ++i) {
    int e = t + i * 256;
    int d = e >> 6, p = e & 63;
    short v;
    if (d < 72)       v = vt[d][p];
    else if (d == 72) v = (short)0x3F80;  // bf16 1.0 -> denominator column
    else              v = 0;
    Vg[(sh * 96 + d) * 1024 + pos0 + p] = v;
  }
}

// ---------------- Flash attention: swapped-QK 32x32, dbuf staging ----------------
// R15: P-pack via v_cvt_pk_bf16_f32 (1 op per bf16-pair vs ~14 for emulated RNE);
//      balanced max tree (depth 5 vs 31). LDS 49KB -> 3 blocks/CU (R14).
#define KSS 88
#define VTS 72
__global__ __launch_bounds__(256, 3) void k_attn(
    const short* __restrict__ Qg, const short* __restrict__ Kg, const short* __restrict__ Vg,
    short* __restrict__ Og)
{
  __shared__ __align__(16) short Ks[2][64 * KSS];   // 11 chunks/row (10 data + 1 pad)
  __shared__ __align__(16) short VT[2][96 * VTS];   // 9 chunks/row (8 data + 1 pad)
  const int p_ = blockIdx.x;
  const int xcd = p_ & 7, rest = p_ >> 3;
  const int qb = rest & 7, shi = rest >> 3;
  const int sh = xcd * 16 + shi;
  const int seg = sh >> 4, head = sh & 15;
  const int t = threadIdx.x, lane = t & 63, wave = t >> 6;
  const int l31 = lane & 31, hi = lane >> 5;
  const int q0 = qb * 128 + wave * 32;

  bf16x8 qf[5];
  {
    const short* qp = Qg + ((size_t)(sh * 1024 + q0 + l31)) * 96 + hi * 8;
#pragma unroll
    for (int dm = 0; dm < 5; ++dm) qf[dm] = *(const bf16x8*)(qp + dm * 16);
  }

  const short* kbase = Kg + (size_t)sh * 1024 * 96;
  const short* vbase = Vg + (size_t)sh * 96 * 1024;
  int koff[3], voff[4];
#pragma unroll
  for (int i = 0; i < 3; ++i) {
    int c = t + i * 256;
    int kr = c / 11, kc8 = c - kr * 11;
    koff[i] = kr * 96 + ((kc8 == 10) ? 0 : kc8 * 8);
  }
#pragma unroll
  for (int i = 0; i < 4; ++i) {
    int c = t + i * 256;
    int vr = c / 9, vc8 = c - vr * 9;
    voff[i] = vr * 1024 + ((vc8 == 8) ? 0 : vc8 * 8);
  }

#define STAGE_KV(buf, kt_) do { \
    const short* kp = kbase + (kt_) * 64 * 96; \
    const short* vp = vbase + (kt_) * 64; \
    _Pragma("unroll") \
    for (int i = 0; i < 2; ++i) { \
      gload16(kp + koff[i], (char*)Ks[buf] + (t + i * 256) * 16); \
      gload16(vp + voff[i], (char*)VT[buf] + (t + i * 256) * 16); \
    } \
    gload16(vp + voff[2], (char*)VT[buf] + (t + 512) * 16); \
    if (t < 192) gload16(kp + koff[2], (char*)Ks[buf] + (t + 512) * 16); \
    if (t < 96)  gload16(vp + voff[3], (char*)VT[buf] + (t + 768) * 16); \
  } while (0)

  f32x16 acc0 = {}, acc1 = {}, acc2 = {};
  float Mrun = -1e30f;

  STAGE_KV(0, 0);
  __syncthreads();

  for (int kt = 0; kt < 16; ++kt) {
    const int cur = kt & 1;
    if (kt < 15) STAGE_KV(cur ^ 1, kt + 1);

    f32x16 s0 = {}, s1 = {};
    __builtin_amdgcn_s_setprio(1);
#pragma unroll
    for (int dm = 0; dm < 5; ++dm) {
      bf16x8 kf0 = *(const bf16x8*)&Ks[cur][l31 * KSS + dm * 16 + hi * 8];
      bf16x8 kf1 = *(const bf16x8*)&Ks[cur][(32 + l31) * KSS + dm * 16 + hi * 8];
      s0 = __builtin_amdgcn_mfma_f32_32x32x16_bf16(kf0, qf[dm], s0, 0, 0, 0);
      s1 = __builtin_amdgcn_mfma_f32_32x32x16_bf16(kf1, qf[dm], s1, 0, 0, 0);
    }
    __builtin_amdgcn_s_setprio(0);

    // balanced max tree: depth 5 instead of serial 31-chain
    float mx[16];
#pragma unroll
    for (int r = 0; r < 16; ++r) mx[r] = fmaxf(s0[r], s1[r]);
#pragma unroll
    for (int st = 8; st > 0; st >>= 1)
#pragma unroll
      for (int r = 0; r < st; ++r) mx[r] = fmaxf(mx[r], mx[r + st]);
    float pmax = fmaxf(mx[0], __shfl_xor(mx[0], 32));

    if (__any(pmax > Mrun + 8.0f)) {
      float mn = fmaxf(Mrun, pmax);
      float corr = exp2f(Mrun - mn);
      Mrun = mn;
#pragma unroll
      for (int r = 0; r < 16; ++r) {
        int qr = (r & 3) + 8 * (r >> 2) + 4 * hi;
        float cr = __shfl(corr, qr);
        acc0[r] *= cr; acc1[r] *= cr; acc2[r] *= cr;
      }
    }

    // P = exp2(s - M); pack pairs with HW v_cvt_pk_bf16_f32 (1 op each)
    unsigned int pk0[8], pk1[8];
#pragma unroll
    for (int b = 0; b < 4; ++b)
#pragma unroll
      for (int i = 0; i < 2; ++i) {
        pk0[b * 2 + i] = pkcvt(exp2f(s0[b * 4 + 2 * i] - Mrun), exp2f(s0[b * 4 + 2 * i + 1] - Mrun));
        pk1[b * 2 + i] = pkcvt(exp2f(s1[b * 4 + 2 * i] - Mrun), exp2f(s1[b * 4 + 2 * i + 1] - Mrun));
      }

    __builtin_amdgcn_s_setprio(1);
#pragma unroll
    for (int ks = 0; ks < 4; ++ks) {
      const int k1 = ks & 1;
      unsigned int A0, A1, B0, B1;
      if (ks < 2) { A0 = pk0[4 * k1]; A1 = pk0[4 * k1 + 1]; B0 = pk0[4 * k1 + 2]; B1 = pk0[4 * k1 + 3]; }
      else        { A0 = pk1[4 * k1]; A1 = pk1[4 * k1 + 1]; B0 = pk1[4 * k1 + 2]; B1 = pk1[4 * k1 + 3]; }
      unsigned int x0 = A0, z0 = B0, y0 = A1, w0 = B1;
      asm volatile("v_permlane32_swap_b32 %0, %1" : "+v"(x0), "+v"(z0));
      asm volatile("v_permlane32_swap_b32 %0, %1" : "+v"(y0), "+v"(w0));
      u32x4 wv;
      wv.x = x0; wv.y = y0; wv.z = z0; wv.w = w0;
      bf16x8 af = __builtin_bit_cast(bf16x8, wv);
      bf16x8 vf0 = *(const bf16x8*)&VT[cur][l31 * VTS + ks * 16 + hi * 8];
      bf16x8 vf1 = *(const bf16x8*)&VT[cur][(32 + l31) * VTS + ks * 16 + hi * 8];
      bf16x8 vf2 = *(const bf16x8*)&VT[cur][(64 + l31) * VTS + ks * 16 + hi * 8];
      acc0 = __builtin_amdgcn_mfma_f32_32x32x16_bf16(af, vf0, acc0, 0, 0, 0);
      acc1 = __builtin_amdgcn_mfma_f32_32x32x16_bf16(af, vf1, acc1, 0, 0, 0);
      acc2 = __builtin_amdgcn_mfma_f32_32x32x16_bf16(af, vf2, acc2, 0, 0, 0);
    }
    __builtin_amdgcn_s_setprio(0);

    __syncthreads();
  }
#undef STAGE_KV

#pragma unroll
  for (int r = 0; r < 16; ++r) {
    float l = __shfl(acc2[r], (lane & 32) | 8);
    float inv = 1.0f / l;
    int q = q0 + (r & 3) + 8 * (r >> 2) + 4 * hi;
    size_t base = (size_t)(seg * 1024 + q) * 1152 + head * 72;
    Og[base + l31]      = f2b(acc0[r] * inv);
    Og[base + 32 + l31] = f2b(acc1[r] * inv);
    if (l31 < 8) Og[base + 64 + l31] = f2b(acc2[r] * inv);
  }
}

// ---------------- launch ----------------
extern "C" void kernel_launch(void* const* d_in, const int* in_sizes, int n_in,
                              void* d_out, int out_size, void* d_ws, size_t ws_size,
                              hipStream_t stream) {
  (void)in_sizes; (void)n_in; (void)out_size; (void)ws_size;
  const float* x      = (const float*)d_in[0];
  const float* cosb   = (const float*)d_in[1];
  const float* sinb   = (const float*)d_in[2];
  const float* qkv_w  = (const float*)d_in[3];
  const float* qkv_b  = (const float*)d_in[4];
  const float* proj_w = (const float*)d_in[5];
  const float* proj_b = (const float*)d_in[6];

  char* ws = (char*)d_ws;
  size_t o = 0;
  short* xb  = (short*)(ws + o); o += (size_t)SS * EE * 2;
  short* qwb = (short*)(ws + o); o += (size_t)E3 * EE * 2;
  short* pwb = (short*)(ws + o); o += (size_t)EE * EE * 2;
  short* qkv = (short*)(ws + o); o += (size_t)SS * E3 * 2;
  short* Qg  = (short*)(ws + o); o += (size_t)SEGN * HH * LSEG * DP * 2;
  short* Kg  = (short*)(ws + o); o += (size_t)SEGN * HH * LSEG * DP * 2;
  short* Vg  = (short*)(ws + o); o += (size_t)SEGN * HH * DP * LSEG * 2;
  short* og  = xb; // x dead after GEMM1

  k_cvt<<<2048, 256, 0, stream>>>(x, xb, SS * EE / 4);
  k_cvt<<<1024, 256, 0, stream>>>(qkv_w, qwb, E3 * EE / 4);
  k_cvt<<<512, 256, 0, stream>>>(proj_w, pwb, EE * EE / 4);

  dim3 g1(SS / 128, E3 / 128);    // 64 x 27 = 1728 blocks, 4/CU co-resident
  k_gemm128<1><<<g1, 256, 0, stream>>>(xb, qwb, qkv_b, qkv, EE, E3);

  k_rope<<<SEGN * HH * 16, 256, 0, stream>>>(qkv, cosb, sinb, Qg, Kg, Vg);

  k_attn<<<SEGN * HH * 8, 256, 0, stream>>>(Qg, Kg, Vg, og);

  dim3 g2(SS / 128, EE / 128);    // 64 x 9 = 576 blocks
  k_gemm128<0><<<g2, 256, 0, stream>>>(og, pwb, proj_b, d_out, EE, EE);
}